// Round 7
// baseline (371.772 us; speedup 1.0000x reference)
//
#include <hip/hip_runtime.h>

#define N_NODES 100000
#define N_EDGES 1600000
#define N_GRAPHS 512
#define HDIM 128
#define HP 64        // packed u32 per row (2 bf16 each)
#define OUTDIM 64
#define NBUCK 391    // buckets of 256 dst nodes
#define SLAB 6144    // max edges per bucket (mean 4092, +32 sigma)
#define EPB 4096     // edges per k_bucket block

typedef short short8 __attribute__((ext_vector_type(8)));
typedef float f32x4 __attribute__((ext_vector_type(4)));
union FragU { uint4 u; short8 s; };

__device__ __forceinline__ float bflo(unsigned u) { return __uint_as_float(u << 16); }
__device__ __forceinline__ float bfhi(unsigned u) { return __uint_as_float(u & 0xffff0000u); }
__device__ __forceinline__ unsigned bf16r(float f) {
    unsigned u = __float_as_uint(f);
    return (u + 0x7fffu + ((u >> 16) & 1u)) >> 16;
}
__device__ __forceinline__ unsigned packbf(float a, float b) {
    return bf16r(a) | (bf16r(b) << 16);
}

// ---------------- phase A: bucket scatter with block-local reservation ----------------
__global__ __launch_bounds__(256) void k_bucket(const int* __restrict__ src,
                                                const int* __restrict__ dst,
                                                int* __restrict__ gcur,
                                                unsigned* __restrict__ ebuck) {
    __shared__ int hist[NBUCK];
    __shared__ int base[NBUCK];
    __shared__ int cur[NBUCK];
    const int t = threadIdx.x;
    const int e0 = blockIdx.x * EPB;
    for (int b = t; b < NBUCK; b += 256) hist[b] = 0;
    __syncthreads();
    for (int i = t; i < EPB; i += 256) {
        int e = e0 + i;
        if (e < N_EDGES) atomicAdd(&hist[dst[e] >> 8], 1);
    }
    __syncthreads();
    for (int b = t; b < NBUCK; b += 256) {
        base[b] = atomicAdd(&gcur[b], hist[b]);
        cur[b] = 0;
    }
    __syncthreads();
    for (int i = t; i < EPB; i += 256) {
        int e = e0 + i;
        if (e < N_EDGES) {
            int d = dst[e], s = src[e];
            int b = d >> 8;
            int p = base[b] + atomicAdd(&cur[b], 1);
            if (p < SLAB)
                ebuck[(size_t)b * SLAB + p] = ((unsigned)s << 8) | (unsigned)(d & 255);
        }
    }
}

// ---------------- phase B: per-bucket exact sort + rbase/rend/dinv ----------------
// esrc stores the src-row BYTE offset (s*256) directly.
__global__ __launch_bounds__(256) void k_bsort(const int* __restrict__ gcur,
                                               const unsigned* __restrict__ ebuck,
                                               unsigned* __restrict__ esrc,
                                               int* __restrict__ rbase,
                                               int* __restrict__ rend,
                                               float* __restrict__ dinv) {
    __shared__ unsigned stage[SLAB];   // 24 KB
    __shared__ int hist[256], offs[256], cur[256];
    __shared__ int wsum[4];
    const int t = threadIdx.x;
    const int b = blockIdx.x;
    const int cnt = min(gcur[b], SLAB);
    hist[t] = 0;
    cur[t] = 0;
    __syncthreads();
    for (int i = t; i < cnt; i += 256) {
        unsigned u = ebuck[(size_t)b * SLAB + i];
        stage[i] = u;
        atomicAdd(&hist[u & 255], 1);
    }
    __syncthreads();
    int v = hist[t];
    int lane = t & 63, wv = t >> 6;
    int incl = v;
#pragma unroll
    for (int o = 1; o < 64; o <<= 1) {
        int tmp = __shfl_up(incl, o);
        if (lane >= o) incl += tmp;
    }
    if (lane == 63) wsum[wv] = incl;
    __syncthreads();
    int woff = 0;
    for (int w = 0; w < wv; ++w) woff += wsum[w];
    int ex = incl - v + woff;
    offs[t] = ex;
    int d = b * 256 + t;
    if (d < N_NODES) {
        rbase[d] = b * SLAB + ex;
        rend[d] = b * SLAB + ex + v;
        dinv[d] = rsqrtf((float)v + 1.0f);
    }
    __syncthreads();
    for (int i = t; i < cnt; i += 256) {
        unsigned u = stage[i];
        int dl = u & 255;
        int p = atomicAdd(&cur[dl], 1);
        esrc[b * SLAB + offs[dl] + p] = u & 0xFFFFFF00u;  // byte offset of src row
    }
}

// ---------------- W -> MFMA B-fragment layout (bf16 packed) ----------------
__global__ __launch_bounds__(256) void k_wprep(const float* __restrict__ W0,
                                               const float* __restrict__ W1,
                                               const float* __restrict__ W2,
                                               unsigned* __restrict__ Wfrag) {
    int gid = blockIdx.x * 256 + threadIdx.x;
    if (gid >= 3 * 8192) return;
    int l = gid >> 13;
    int rem = gid & 8191;
    int f = rem >> 8;
    int lane = (rem >> 2) & 63;
    int j = rem & 3;
    int ct = f >> 2, ks = f & 3;
    int n = ct * 16 + (lane & 15);
    int k0 = ks * 32 + (lane >> 4) * 8 + j * 2;
    const float* W = (l == 0) ? W0 : ((l == 1) ? W1 : W2);
    Wfrag[gid] = packbf(W[k0 * HDIM + n], W[(k0 + 1) * HDIM + n]);
}

// ---------------- MFMA GEMM: Cb = (X @ W) * dinv[row], bf16 out ----------------
// 8 live B-frags (per-ks) -> ~100 VGPR -> 4 waves/SIMD occupancy
__global__ __launch_bounds__(256, 4) void k_mgemm(const uint4* __restrict__ Xb4,
                                                  const float4* __restrict__ Xf4,
                                                  const uint4* __restrict__ Wfrag,
                                                  const float* __restrict__ dinv,
                                                  unsigned short* __restrict__ Cbh) {
    const int t = threadIdx.x;
    const int lane = t & 63;
    const int w = t >> 6;
    const int row0 = blockIdx.x * 64 + w * 16;
    const int lhi = lane >> 4;

    f32x4 acc[8];
#pragma unroll
    for (int ct = 0; ct < 8; ++ct) acc[ct] = (f32x4){0.f, 0.f, 0.f, 0.f};

    int arow = row0 + (lane & 15);
    int anode = (arow < N_NODES) ? arow : 0;
#pragma unroll
    for (int ks = 0; ks < 4; ++ks) {
        FragU B[8];
#pragma unroll
        for (int ct = 0; ct < 8; ++ct)
            B[ct].u = Wfrag[(ct * 4 + ks) * 64 + lane];
        FragU a;
        if (Xf4) {
            float4 p = Xf4[(size_t)anode * 32 + ks * 8 + lhi * 2];
            float4 q = Xf4[(size_t)anode * 32 + ks * 8 + lhi * 2 + 1];
            a.u.x = packbf(p.x, p.y);
            a.u.y = packbf(p.z, p.w);
            a.u.z = packbf(q.x, q.y);
            a.u.w = packbf(q.z, q.w);
        } else {
            a.u = Xb4[(size_t)anode * 16 + ks * 4 + lhi];
        }
#pragma unroll
        for (int ct = 0; ct < 8; ++ct)
            acc[ct] = __builtin_amdgcn_mfma_f32_16x16x32_bf16(a.s, B[ct].s, acc[ct], 0, 0, 0);
    }

    int rb = row0 + lhi * 4;
#pragma unroll
    for (int r = 0; r < 4; ++r) {
        int row = rb + r;
        if (row < N_NODES) {
            float dv = dinv[row];
#pragma unroll
            for (int ct = 0; ct < 8; ++ct) {
                int col = ct * 16 + (lane & 15);
                Cbh[(size_t)row * HDIM + col] = (unsigned short)bf16r(acc[ct][r] * dv);
            }
        }
    }
}

// ---------------- shared per-node gather + LN core ----------------
// All 64 lanes return the 8 normalized outputs for node i.
// lane = m (0..15) column group + grp (0..3) edge sub-slot.
__device__ __forceinline__ void gather_node(int i, const char* cbB, unsigned moff, int grp,
                                            const int* __restrict__ rbase,
                                            const int* __restrict__ rend,
                                            const unsigned* __restrict__ esrc,
                                            const float* __restrict__ dinv,
                                            const float4& b0, const float4& b1,
                                            const float4& g0, const float4& g1,
                                            const float4& e0v, const float4& e1v,
                                            float* __restrict__ o) {
    int r0 = rbase[i], r1 = rend[i];
    float acc[8];
#pragma unroll
    for (int c = 0; c < 8; ++c) acc[c] = 0.f;

    int j = r0;
    for (; j + 8 <= r1; j += 8) {
        unsigned o0 = esrc[j + grp];
        unsigned o1 = esrc[j + 4 + grp];
        uint4 v0 = *reinterpret_cast<const uint4*>(cbB + (o0 + moff));
        uint4 v1 = *reinterpret_cast<const uint4*>(cbB + (o1 + moff));
        acc[0] += __uint_as_float(v0.x << 16); acc[1] += __uint_as_float(v0.x);
        acc[2] += __uint_as_float(v0.y << 16); acc[3] += __uint_as_float(v0.y);
        acc[4] += __uint_as_float(v0.z << 16); acc[5] += __uint_as_float(v0.z);
        acc[6] += __uint_as_float(v0.w << 16); acc[7] += __uint_as_float(v0.w);
        acc[0] += __uint_as_float(v1.x << 16); acc[1] += __uint_as_float(v1.x);
        acc[2] += __uint_as_float(v1.y << 16); acc[3] += __uint_as_float(v1.y);
        acc[4] += __uint_as_float(v1.z << 16); acc[5] += __uint_as_float(v1.z);
        acc[6] += __uint_as_float(v1.w << 16); acc[7] += __uint_as_float(v1.w);
    }
    for (; j < r1; j += 4) {
        int e = j + grp;
        bool valid = e < r1;
        unsigned oo = esrc[e];  // esrc padded; safe to over-read
        oo = valid ? oo : (unsigned)(i << 8);
        uint4 v = *reinterpret_cast<const uint4*>(cbB + (oo + moff));
        if (!valid) { v.x = 0; v.y = 0; v.z = 0; v.w = 0; }
        acc[0] += __uint_as_float(v.x << 16); acc[1] += __uint_as_float(v.x);
        acc[2] += __uint_as_float(v.y << 16); acc[3] += __uint_as_float(v.y);
        acc[4] += __uint_as_float(v.z << 16); acc[5] += __uint_as_float(v.z);
        acc[6] += __uint_as_float(v.w << 16); acc[7] += __uint_as_float(v.w);
    }
#pragma unroll
    for (int c = 0; c < 8; ++c) {
        acc[c] += __shfl_xor(acc[c], 16);
        acc[c] += __shfl_xor(acc[c], 32);
    }
    {
        uint4 us = *reinterpret_cast<const uint4*>(cbB + (((unsigned)i << 8) + moff));
        acc[0] += __uint_as_float(us.x << 16); acc[1] += __uint_as_float(us.x);
        acc[2] += __uint_as_float(us.y << 16); acc[3] += __uint_as_float(us.y);
        acc[4] += __uint_as_float(us.z << 16); acc[5] += __uint_as_float(us.z);
        acc[6] += __uint_as_float(us.w << 16); acc[7] += __uint_as_float(us.w);
    }
    float di = dinv[i];
    float vv[8];
    vv[0] = acc[0] * di + b0.x; vv[1] = acc[1] * di + b0.y;
    vv[2] = acc[2] * di + b0.z; vv[3] = acc[3] * di + b0.w;
    vv[4] = acc[4] * di + b1.x; vv[5] = acc[5] * di + b1.y;
    vv[6] = acc[6] * di + b1.z; vv[7] = acc[7] * di + b1.w;
    float s = 0.f, sq = 0.f;
#pragma unroll
    for (int c = 0; c < 8; ++c) { s += vv[c]; sq += vv[c] * vv[c]; }
#pragma unroll
    for (int of = 1; of < 16; of <<= 1) {
        s += __shfl_xor(s, of);
        sq += __shfl_xor(sq, of);
    }
    float mean = s * (1.0f / HDIM);
    float var = sq * (1.0f / HDIM) - mean * mean;
    float rs = rsqrtf(var + 1e-5f);
    o[0] = fmaxf((vv[0] - mean) * rs * g0.x + e0v.x, 0.f);
    o[1] = fmaxf((vv[1] - mean) * rs * g0.y + e0v.y, 0.f);
    o[2] = fmaxf((vv[2] - mean) * rs * g0.z + e0v.z, 0.f);
    o[3] = fmaxf((vv[3] - mean) * rs * g0.w + e0v.w, 0.f);
    o[4] = fmaxf((vv[4] - mean) * rs * g1.x + e1v.x, 0.f);
    o[5] = fmaxf((vv[5] - mean) * rs * g1.y + e1v.y, 0.f);
    o[6] = fmaxf((vv[6] - mean) * rs * g1.z + e1v.z, 0.f);
    o[7] = fmaxf((vv[7] - mean) * rs * g1.w + e1v.w, 0.f);
}

// ---------------- gather (layers 0,1): strided nodes, writes Ab ----------------
__global__ __launch_bounds__(256) void k_gather(const unsigned* __restrict__ Cb,
                                                const int* __restrict__ rbase,
                                                const int* __restrict__ rend,
                                                const unsigned* __restrict__ esrc,
                                                const float* __restrict__ dinv,
                                                const float* __restrict__ b,
                                                const float* __restrict__ g,
                                                const float* __restrict__ be,
                                                unsigned* __restrict__ Ab) {
    const int lane = threadIdx.x & 63;
    const int m = lane & 15;
    const int grp = lane >> 4;
    const char* cbB = (const char*)Cb;
    const unsigned moff = (unsigned)(m << 4);
    int wid = (blockIdx.x * blockDim.x + threadIdx.x) >> 6;
    const int nw = (gridDim.x * blockDim.x) >> 6;

    float4 b0 = reinterpret_cast<const float4*>(b)[m * 2];
    float4 b1 = reinterpret_cast<const float4*>(b)[m * 2 + 1];
    float4 g0 = reinterpret_cast<const float4*>(g)[m * 2];
    float4 g1 = reinterpret_cast<const float4*>(g)[m * 2 + 1];
    float4 e0v = reinterpret_cast<const float4*>(be)[m * 2];
    float4 e1v = reinterpret_cast<const float4*>(be)[m * 2 + 1];

    for (int i = wid; i < N_NODES; i += nw) {
        float o[8];
        gather_node(i, cbB, moff, grp, rbase, rend, esrc, dinv,
                    b0, b1, g0, g1, e0v, e1v, o);
        if (grp == 0) {
            uint4 ov;
            ov.x = packbf(o[0], o[1]);
            ov.y = packbf(o[2], o[3]);
            ov.z = packbf(o[4], o[5]);
            ov.w = packbf(o[6], o[7]);
            reinterpret_cast<uint4*>(Ab + (size_t)i * HP)[m] = ov;
        }
    }
}

// ---------------- gather (layer 2): chunked nodes + fused global-add-pool ----------------
#define PCH 8  // nodes per wave
__global__ __launch_bounds__(256) void k_gatherp(const unsigned* __restrict__ Cb,
                                                 const int* __restrict__ rbase,
                                                 const int* __restrict__ rend,
                                                 const unsigned* __restrict__ esrc,
                                                 const float* __restrict__ dinv,
                                                 const float* __restrict__ b,
                                                 const float* __restrict__ g,
                                                 const float* __restrict__ be,
                                                 const int* __restrict__ batch,
                                                 float* __restrict__ pooled) {
    const int lane = threadIdx.x & 63;
    const int m = lane & 15;
    const int grp = lane >> 4;
    const char* cbB = (const char*)Cb;
    const unsigned moff = (unsigned)(m << 4);
    int wid = (blockIdx.x * blockDim.x + threadIdx.x) >> 6;

    float4 b0 = reinterpret_cast<const float4*>(b)[m * 2];
    float4 b1 = reinterpret_cast<const float4*>(b)[m * 2 + 1];
    float4 g0 = reinterpret_cast<const float4*>(g)[m * 2];
    float4 g1 = reinterpret_cast<const float4*>(g)[m * 2 + 1];
    float4 e0v = reinterpret_cast<const float4*>(be)[m * 2];
    float4 e1v = reinterpret_cast<const float4*>(be)[m * 2 + 1];

    int i0 = wid * PCH;
    if (i0 >= N_NODES) return;
    int i1 = min(i0 + PCH, N_NODES);

    float pacc[8];
#pragma unroll
    for (int c = 0; c < 8; ++c) pacc[c] = 0.f;
    int curb = batch[i0];

    for (int i = i0; i < i1; ++i) {
        float o[8];
        gather_node(i, cbB, moff, grp, rbase, rend, esrc, dinv,
                    b0, b1, g0, g1, e0v, e1v, o);
        int bg = batch[i];
        if (bg != curb) {
            if (grp == 0) {
                float* p = pooled + (size_t)curb * HDIM + m * 8;
#pragma unroll
                for (int c = 0; c < 8; ++c) atomicAdd(p + c, pacc[c]);
            }
#pragma unroll
            for (int c = 0; c < 8; ++c) pacc[c] = 0.f;
            curb = bg;
        }
#pragma unroll
        for (int c = 0; c < 8; ++c) pacc[c] += o[c];
    }
    if (grp == 0) {
        float* p = pooled + (size_t)curb * HDIM + m * 8;
#pragma unroll
        for (int c = 0; c < 8; ++c) atomicAdd(p + c, pacc[c]);
    }
}

// ---------------- head: out = pooled @ Wf + bf ----------------
__global__ __launch_bounds__(256) void k_head(const float* __restrict__ pooled,
                                              const float* __restrict__ Wf,
                                              const float* __restrict__ bf,
                                              float* __restrict__ out) {
    int idx = blockIdx.x * blockDim.x + threadIdx.x;
    if (idx >= N_GRAPHS * OUTDIM) return;
    int gI = idx / OUTDIM;
    int o = idx % OUTDIM;
    float acc = bf[o];
    const float* pr = pooled + (size_t)gI * HDIM;
#pragma unroll 8
    for (int k = 0; k < HDIM; ++k) acc += pr[k] * Wf[k * OUTDIM + o];
    out[idx] = acc;
}

extern "C" void kernel_launch(void* const* d_in, const int* in_sizes, int n_in,
                              void* d_out, int out_size, void* d_ws, size_t ws_size,
                              hipStream_t stream) {
    const float* x = (const float*)d_in[0];
    const int* ei = (const int*)d_in[1];
    const int* src = ei;
    const int* dst = ei + N_EDGES;
    const int* batch = (const int*)d_in[2];
    const float* W[3] = {(const float*)d_in[3], (const float*)d_in[7], (const float*)d_in[11]};
    const float* bb[3] = {(const float*)d_in[4], (const float*)d_in[8], (const float*)d_in[12]};
    const float* gg[3] = {(const float*)d_in[5], (const float*)d_in[9], (const float*)d_in[13]};
    const float* be[3] = {(const float*)d_in[6], (const float*)d_in[10], (const float*)d_in[14]};
    const float* Wf = (const float*)d_in[15];
    const float* bf = (const float*)d_in[16];
    float* out = (float*)d_out;

    char* ws = (char*)d_ws;
    float* dinv = (float*)ws;        ws += sizeof(float) * (N_NODES + 64);
    unsigned* Ab = (unsigned*)ws;    ws += sizeof(unsigned) * (size_t)N_NODES * HP;
    unsigned* Cb = (unsigned*)ws;    ws += sizeof(unsigned) * (size_t)N_NODES * HP;
    unsigned* Wfrag = (unsigned*)ws; ws += sizeof(unsigned) * 3 * 8192;
    float* pooled = (float*)ws;      ws += sizeof(float) * N_GRAPHS * HDIM;
    int* rbase = (int*)ws;           ws += sizeof(int) * (N_NODES + 64);
    int* rend = (int*)ws;            ws += sizeof(int) * (N_NODES + 64);
    int* gcur = (int*)ws;            ws += sizeof(int) * (NBUCK + 64);
    unsigned* ebuck = (unsigned*)ws; ws += sizeof(unsigned) * (size_t)NBUCK * SLAB;
    unsigned* esrc = (unsigned*)ws;  ws += sizeof(unsigned) * ((size_t)NBUCK * SLAB + 64);

    hipMemsetAsync(gcur, 0, NBUCK * sizeof(int), stream);
    hipMemsetAsync(pooled, 0, N_GRAPHS * HDIM * sizeof(float), stream);
    k_bucket<<<(N_EDGES + EPB - 1) / EPB, 256, 0, stream>>>(src, dst, gcur, ebuck);
    k_bsort<<<NBUCK, 256, 0, stream>>>(gcur, ebuck, esrc, rbase, rend, dinv);
    k_wprep<<<96, 256, 0, stream>>>(W[0], W[1], W[2], Wfrag);

    const int gemm_blocks = (N_NODES + 63) / 64;
    for (int l = 0; l < 3; ++l) {
        k_mgemm<<<gemm_blocks, 256, 0, stream>>>(
            l == 0 ? nullptr : (const uint4*)Ab,
            l == 0 ? (const float4*)x : nullptr,
            (const uint4*)(Wfrag + l * 8192), dinv, (unsigned short*)Cb);
        if (l < 2) {
            k_gather<<<25000, 256, 0, stream>>>(Cb, rbase, rend, esrc, dinv,
                                                bb[l], gg[l], be[l], Ab);
        } else {
            const int pw = (N_NODES + PCH - 1) / PCH;        // waves
            k_gatherp<<<(pw + 3) / 4, 256, 0, stream>>>(Cb, rbase, rend, esrc, dinv,
                                                        bb[l], gg[l], be[l], batch, pooled);
        }
    }

    k_head<<<(N_GRAPHS * OUTDIM + 255) / 256, 256, 0, stream>>>(pooled, Wf, bf, out);
}

// Round 9
// 321.781 us; speedup vs baseline: 1.1554x; 1.1554x over previous
//
#include <hip/hip_runtime.h>

#define N_NODES 100000
#define N_EDGES 1600000
#define N_GRAPHS 512
#define HDIM 128
#define HP 64        // packed u32 per row (2 bf16 each)
#define OUTDIM 64
#define NBUCK 391    // buckets of 256 dst nodes
#define SLAB 6144    // max edges per bucket (mean 4092, +32 sigma)
#define EPB 4096     // edges per k_bucket block
#define ZOFF ((unsigned)N_NODES * 256u)  // byte offset of the all-zero row

typedef short short8 __attribute__((ext_vector_type(8)));
typedef float f32x4 __attribute__((ext_vector_type(4)));
union FragU { uint4 u; short8 s; };

__device__ __forceinline__ float bflo(unsigned u) { return __uint_as_float(u << 16); }
__device__ __forceinline__ float bfhi(unsigned u) { return __uint_as_float(u & 0xffff0000u); }
__device__ __forceinline__ unsigned bf16r(float f) {
    unsigned u = __float_as_uint(f);
    return (u + 0x7fffu + ((u >> 16) & 1u)) >> 16;
}
__device__ __forceinline__ unsigned packbf(float a, float b) {
    return bf16r(a) | (bf16r(b) << 16);
}

// ---------------- phase A: bucket scatter with block-local reservation ----------------
__global__ __launch_bounds__(256) void k_bucket(const int* __restrict__ src,
                                                const int* __restrict__ dst,
                                                int* __restrict__ gcur,
                                                unsigned* __restrict__ ebuck) {
    __shared__ int hist[NBUCK];
    __shared__ int base[NBUCK];
    __shared__ int cur[NBUCK];
    const int t = threadIdx.x;
    const int e0 = blockIdx.x * EPB;
    for (int b = t; b < NBUCK; b += 256) hist[b] = 0;
    __syncthreads();
    for (int i = t; i < EPB; i += 256) {
        int e = e0 + i;
        if (e < N_EDGES) atomicAdd(&hist[dst[e] >> 8], 1);
    }
    __syncthreads();
    for (int b = t; b < NBUCK; b += 256) {
        base[b] = atomicAdd(&gcur[b], hist[b]);
        cur[b] = 0;
    }
    __syncthreads();
    for (int i = t; i < EPB; i += 256) {
        int e = e0 + i;
        if (e < N_EDGES) {
            int d = dst[e], s = src[e];
            int b = d >> 8;
            int p = base[b] + atomicAdd(&cur[b], 1);
            if (p < SLAB)
                ebuck[(size_t)b * SLAB + p] = ((unsigned)s << 8) | (unsigned)(d & 255);
        }
    }
}

// ---------------- phase B: per-bucket exact sort + rbase/rend/dinv ----------------
// esrc stores the src-row BYTE offset (s*256) directly.
__global__ __launch_bounds__(256) void k_bsort(const int* __restrict__ gcur,
                                               const unsigned* __restrict__ ebuck,
                                               unsigned* __restrict__ esrc,
                                               int* __restrict__ rbase,
                                               int* __restrict__ rend,
                                               float* __restrict__ dinv) {
    __shared__ unsigned stage[SLAB];   // 24 KB
    __shared__ int hist[256], offs[256], cur[256];
    __shared__ int wsum[4];
    const int t = threadIdx.x;
    const int b = blockIdx.x;
    const int cnt = min(gcur[b], SLAB);
    hist[t] = 0;
    cur[t] = 0;
    __syncthreads();
    for (int i = t; i < cnt; i += 256) {
        unsigned u = ebuck[(size_t)b * SLAB + i];
        stage[i] = u;
        atomicAdd(&hist[u & 255], 1);
    }
    __syncthreads();
    int v = hist[t];
    int lane = t & 63, wv = t >> 6;
    int incl = v;
#pragma unroll
    for (int o = 1; o < 64; o <<= 1) {
        int tmp = __shfl_up(incl, o);
        if (lane >= o) incl += tmp;
    }
    if (lane == 63) wsum[wv] = incl;
    __syncthreads();
    int woff = 0;
    for (int w = 0; w < wv; ++w) woff += wsum[w];
    int ex = incl - v + woff;
    offs[t] = ex;
    int d = b * 256 + t;
    if (d < N_NODES) {
        rbase[d] = b * SLAB + ex;
        rend[d] = b * SLAB + ex + v;
        dinv[d] = rsqrtf((float)v + 1.0f);
    }
    __syncthreads();
    for (int i = t; i < cnt; i += 256) {
        unsigned u = stage[i];
        int dl = u & 255;
        int p = atomicAdd(&cur[dl], 1);
        esrc[b * SLAB + offs[dl] + p] = u & 0xFFFFFF00u;  // byte offset of src row
    }
}

// ---------------- W -> MFMA B-fragment layout (bf16 packed) ----------------
__global__ __launch_bounds__(256) void k_wprep(const float* __restrict__ W0,
                                               const float* __restrict__ W1,
                                               const float* __restrict__ W2,
                                               unsigned* __restrict__ Wfrag) {
    int gid = blockIdx.x * 256 + threadIdx.x;
    if (gid >= 3 * 8192) return;
    int l = gid >> 13;
    int rem = gid & 8191;
    int f = rem >> 8;
    int lane = (rem >> 2) & 63;
    int j = rem & 3;
    int ct = f >> 2, ks = f & 3;
    int n = ct * 16 + (lane & 15);
    int k0 = ks * 32 + (lane >> 4) * 8 + j * 2;
    const float* W = (l == 0) ? W0 : ((l == 1) ? W1 : W2);
    Wfrag[gid] = packbf(W[k0 * HDIM + n], W[(k0 + 1) * HDIM + n]);
}

// ---------------- MFMA GEMM: Cb = (X @ W) * dinv[row], bf16 out ----------------
// LDS-staged epilogue for coalesced uint4 stores.
__global__ __launch_bounds__(256, 2) void k_mgemm(const uint4* __restrict__ Xb4,
                                                  const float4* __restrict__ Xf4,
                                                  const uint4* __restrict__ Wfrag,
                                                  const float* __restrict__ dinv,
                                                  unsigned short* __restrict__ Cbh) {
    __shared__ __align__(16) unsigned short Cs[64][136];  // pad: row stride 272B (17x16B)
    const int t = threadIdx.x;
    const int lane = t & 63;
    const int w = t >> 6;
    const int brow0 = blockIdx.x * 64;
    const int row0 = brow0 + w * 16;
    const int lhi = lane >> 4;

    FragU B[8][4];
#pragma unroll
    for (int ct = 0; ct < 8; ++ct)
#pragma unroll
        for (int ks = 0; ks < 4; ++ks)
            B[ct][ks].u = Wfrag[(ct * 4 + ks) * 64 + lane];

    f32x4 acc[8];
#pragma unroll
    for (int ct = 0; ct < 8; ++ct) acc[ct] = (f32x4){0.f, 0.f, 0.f, 0.f};

    int arow = row0 + (lane & 15);
    int anode = (arow < N_NODES) ? arow : 0;
#pragma unroll
    for (int ks = 0; ks < 4; ++ks) {
        FragU a;
        if (Xf4) {
            float4 p = Xf4[(size_t)anode * 32 + ks * 8 + lhi * 2];
            float4 q = Xf4[(size_t)anode * 32 + ks * 8 + lhi * 2 + 1];
            a.u.x = packbf(p.x, p.y);
            a.u.y = packbf(p.z, p.w);
            a.u.z = packbf(q.x, q.y);
            a.u.w = packbf(q.z, q.w);
        } else {
            a.u = Xb4[(size_t)anode * 16 + ks * 4 + lhi];
        }
#pragma unroll
        for (int ct = 0; ct < 8; ++ct)
            acc[ct] = __builtin_amdgcn_mfma_f32_16x16x32_bf16(a.s, B[ct][ks].s, acc[ct], 0, 0, 0);
    }

    // accumulators -> LDS (bf16), dinv-scaled
#pragma unroll
    for (int r = 0; r < 4; ++r) {
        int lrow = w * 16 + lhi * 4 + r;
        int grow = brow0 + lrow;
        float dv = dinv[(grow < N_NODES) ? grow : 0];
#pragma unroll
        for (int ct = 0; ct < 8; ++ct)
            Cs[lrow][ct * 16 + (lane & 15)] = (unsigned short)bf16r(acc[ct][r] * dv);
    }
    __syncthreads();
    // LDS -> global, full 16B lines: 64 rows x 16 chunks of 8 shorts
#pragma unroll
    for (int u = 0; u < 4; ++u) {
        int idx = t + u * 256;           // 0..1023
        int row = idx >> 4, q = idx & 15;
        if (brow0 + row < N_NODES) {
            uint4 val = *reinterpret_cast<const uint4*>(&Cs[row][q * 8]);
            *reinterpret_cast<uint4*>(Cbh + ((size_t)(brow0 + row) * HDIM + q * 8)) = val;
        }
    }
}

// ---------------- gather + self + bias + layernorm + relu (bf16 rows) ----------------
// 1 node per wave; lane = column (u32 pair); byte-offset esrc; zero-row tail.
__global__ __launch_bounds__(256) void k_gather(const unsigned* __restrict__ Cb,
                                                const int* __restrict__ rbase,
                                                const int* __restrict__ rend,
                                                const unsigned* __restrict__ esrc,
                                                const float* __restrict__ dinv,
                                                const float* __restrict__ b,
                                                const float* __restrict__ g,
                                                const float* __restrict__ be,
                                                unsigned* __restrict__ Ab) {
    const int lane = threadIdx.x & 63;
    const char* cbB = (const char*)Cb;
    const unsigned lb = (unsigned)(lane * 4);
    int wid = (blockIdx.x * blockDim.x + threadIdx.x) >> 6;
    const int nw = (gridDim.x * blockDim.x) >> 6;
    float2 bb = reinterpret_cast<const float2*>(b)[lane];
    float2 gg = reinterpret_cast<const float2*>(g)[lane];
    float2 bee = reinterpret_cast<const float2*>(be)[lane];
    for (int i = wid; i < N_NODES; i += nw) {
        int r0 = rbase[i], r1 = rend[i];
        float ax = 0.f, ay = 0.f;
        for (int j = r0; j < r1; j += 16) {
            unsigned off[16];
#pragma unroll
            for (int q = 0; q < 16; ++q)
                off[q] = (j + q < r1) ? esrc[j + q] : ZOFF;  // padded; zero row kills tail
            unsigned u[16];
#pragma unroll
            for (int q = 0; q < 16; ++q)
                u[q] = *reinterpret_cast<const unsigned*>(cbB + (off[q] + lb));
#pragma unroll
            for (int q = 0; q < 16; ++q) {
                ax += __uint_as_float(u[q] << 16);
                ay += __uint_as_float(u[q]);       // junk low mantissa, <0.8% rel
            }
        }
        // self-loop (row already dinv-scaled)
        unsigned us = *reinterpret_cast<const unsigned*>(cbB + (((unsigned)i << 8) + lb));
        ax += __uint_as_float(us << 16);
        ay += __uint_as_float(us);
        float di = dinv[i];
        float vx = ax * di + bb.x;
        float vy = ay * di + bb.y;
        float s = vx + vy, sq = vx * vx + vy * vy;
#pragma unroll
        for (int o = 1; o < 64; o <<= 1) {
            s += __shfl_xor(s, o);
            sq += __shfl_xor(sq, o);
        }
        float m = s * (1.0f / HDIM);
        float var = sq * (1.0f / HDIM) - m * m;
        float rs = rsqrtf(var + 1e-5f);
        float ox = fmaxf((vx - m) * rs * gg.x + bee.x, 0.f);
        float oy = fmaxf((vy - m) * rs * gg.y + bee.y, 0.f);
        Ab[(size_t)i * HP + lane] = packbf(ox, oy);
    }
}

// ---------------- pool: pooled[batch[i]] += A[i] (bf16 rows, sorted batch) ----------------
__global__ __launch_bounds__(256) void k_pool(const unsigned* __restrict__ Ab,
                                              const int* __restrict__ batch,
                                              float* __restrict__ pooled) {
    const int CH = 16;
    const int lane = threadIdx.x & 63;
    int wid = (blockIdx.x * blockDim.x + threadIdx.x) >> 6;
    const int nw = (gridDim.x * blockDim.x) >> 6;
    const int nchunks = (N_NODES + CH - 1) / CH;
    for (int c = wid; c < nchunks; c += nw) {
        int i0 = c * CH;
        int i1 = min(i0 + CH, N_NODES);
        float ax = 0.f, ay = 0.f;
        int curb = batch[i0];
        for (int i = i0; i < i1; ++i) {
            int bg = batch[i];
            if (bg != curb) {
                float* p = pooled + (size_t)curb * HDIM + lane * 2;
                atomicAdd(p, ax);
                atomicAdd(p + 1, ay);
                ax = 0.f; ay = 0.f;
                curb = bg;
            }
            unsigned v = Ab[(size_t)i * HP + lane];
            ax += bflo(v);
            ay += bfhi(v);
        }
        float* p = pooled + (size_t)curb * HDIM + lane * 2;
        atomicAdd(p, ax);
        atomicAdd(p + 1, ay);
    }
}

// ---------------- head: out = pooled @ Wf + bf ----------------
__global__ __launch_bounds__(256) void k_head(const float* __restrict__ pooled,
                                              const float* __restrict__ Wf,
                                              const float* __restrict__ bf,
                                              float* __restrict__ out) {
    int idx = blockIdx.x * blockDim.x + threadIdx.x;
    if (idx >= N_GRAPHS * OUTDIM) return;
    int gI = idx / OUTDIM;
    int o = idx % OUTDIM;
    float acc = bf[o];
    const float* pr = pooled + (size_t)gI * HDIM;
#pragma unroll 8
    for (int k = 0; k < HDIM; ++k) acc += pr[k] * Wf[k * OUTDIM + o];
    out[idx] = acc;
}

extern "C" void kernel_launch(void* const* d_in, const int* in_sizes, int n_in,
                              void* d_out, int out_size, void* d_ws, size_t ws_size,
                              hipStream_t stream) {
    const float* x = (const float*)d_in[0];
    const int* ei = (const int*)d_in[1];
    const int* src = ei;
    const int* dst = ei + N_EDGES;
    const int* batch = (const int*)d_in[2];
    const float* W[3] = {(const float*)d_in[3], (const float*)d_in[7], (const float*)d_in[11]};
    const float* bb[3] = {(const float*)d_in[4], (const float*)d_in[8], (const float*)d_in[12]};
    const float* gg[3] = {(const float*)d_in[5], (const float*)d_in[9], (const float*)d_in[13]};
    const float* be[3] = {(const float*)d_in[6], (const float*)d_in[10], (const float*)d_in[14]};
    const float* Wf = (const float*)d_in[15];
    const float* bf = (const float*)d_in[16];
    float* out = (float*)d_out;

    char* ws = (char*)d_ws;
    float* dinv = (float*)ws;        ws += sizeof(float) * (N_NODES + 64);
    unsigned* Ab = (unsigned*)ws;    ws += sizeof(unsigned) * (size_t)N_NODES * HP;
    unsigned* Cb = (unsigned*)ws;    ws += sizeof(unsigned) * ((size_t)N_NODES * HP + HP);  // +1 zero row
    unsigned* Wfrag = (unsigned*)ws; ws += sizeof(unsigned) * 3 * 8192;
    float* pooled = (float*)ws;      ws += sizeof(float) * N_GRAPHS * HDIM;
    int* rbase = (int*)ws;           ws += sizeof(int) * (N_NODES + 64);
    int* rend = (int*)ws;            ws += sizeof(int) * (N_NODES + 64);
    int* gcur = (int*)ws;            ws += sizeof(int) * (NBUCK + 64);
    unsigned* ebuck = (unsigned*)ws; ws += sizeof(unsigned) * (size_t)NBUCK * SLAB;
    unsigned* esrc = (unsigned*)ws;  ws += sizeof(unsigned) * ((size_t)NBUCK * SLAB + 64);

    hipMemsetAsync(gcur, 0, NBUCK * sizeof(int), stream);
    hipMemsetAsync(pooled, 0, N_GRAPHS * HDIM * sizeof(float), stream);
    hipMemsetAsync(Cb + (size_t)N_NODES * HP, 0, HP * sizeof(unsigned), stream);  // zero row
    k_bucket<<<(N_EDGES + EPB - 1) / EPB, 256, 0, stream>>>(src, dst, gcur, ebuck);
    k_bsort<<<NBUCK, 256, 0, stream>>>(gcur, ebuck, esrc, rbase, rend, dinv);
    k_wprep<<<96, 256, 0, stream>>>(W[0], W[1], W[2], Wfrag);

    const int gemm_blocks = (N_NODES + 63) / 64;
    for (int l = 0; l < 3; ++l) {
        k_mgemm<<<gemm_blocks, 256, 0, stream>>>(
            l == 0 ? nullptr : (const uint4*)Ab,
            l == 0 ? (const float4*)x : nullptr,
            (const uint4*)(Wfrag + l * 8192), dinv, (unsigned short*)Cb);
        k_gather<<<25000, 256, 0, stream>>>(Cb, rbase, rend, esrc, dinv,
                                            bb[l], gg[l], be[l], Ab);
    }

    k_pool<<<1563, 256, 0, stream>>>(Ab, batch, pooled);
    k_head<<<(N_GRAPHS * OUTDIM + 255) / 256, 256, 0, stream>>>(pooled, Wf, bf, out);
}

// Round 10
// 301.861 us; speedup vs baseline: 1.2316x; 1.0660x over previous
//
#include <hip/hip_runtime.h>

#define N_NODES 100000
#define N_EDGES 1600000
#define N_GRAPHS 512
#define HDIM 128
#define HP 64        // packed u32 per row (2 bf16 each)
#define OUTDIM 64
#define NBUCK 391    // buckets of 256 dst nodes
#define SLAB 6912    // padded slots per bucket (E[sum p] ~6020, sigma ~100)
#define EPB 4096     // edges per k_bucket block
#define ZOFF ((unsigned)N_NODES * 256u)  // byte offset of the all-zero row

typedef short short8 __attribute__((ext_vector_type(8)));
typedef float f32x4 __attribute__((ext_vector_type(4)));
union FragU { uint4 u; short8 s; };

__device__ __forceinline__ float bflo(unsigned u) { return __uint_as_float(u << 16); }
__device__ __forceinline__ float bfhi(unsigned u) { return __uint_as_float(u & 0xffff0000u); }
__device__ __forceinline__ unsigned bf16r(float f) {
    unsigned u = __float_as_uint(f);
    return (u + 0x7fffu + ((u >> 16) & 1u)) >> 16;
}
__device__ __forceinline__ unsigned packbf(float a, float b) {
    return bf16r(a) | (bf16r(b) << 16);
}

// ---------------- init: esrc=ZOFF fill, pooled/gcur/zero-row clear, W-frag prep ----------------
__global__ __launch_bounds__(256) void k_init(const float* __restrict__ W0,
                                              const float* __restrict__ W1,
                                              const float* __restrict__ W2,
                                              unsigned* __restrict__ Wfrag,
                                              unsigned* __restrict__ esrc,
                                              float* __restrict__ pooled,
                                              int* __restrict__ gcur,
                                              unsigned* __restrict__ zrow) {
    int gid = blockIdx.x * 256 + threadIdx.x;
    int gs = gridDim.x * 256;
    for (int i = gid; i < NBUCK * SLAB; i += gs) esrc[i] = ZOFF;
    for (int i = gid; i < N_GRAPHS * HDIM; i += gs) pooled[i] = 0.f;
    for (int i = gid; i < NBUCK; i += gs) gcur[i] = 0;
    for (int i = gid; i < HP; i += gs) zrow[i] = 0u;
    for (int i = gid; i < 3 * 8192; i += gs) {
        int l = i >> 13;
        int rem = i & 8191;
        int f = rem >> 8;
        int lane = (rem >> 2) & 63;
        int j = rem & 3;
        int ct = f >> 2, ks = f & 3;
        int n = ct * 16 + (lane & 15);
        int k0 = ks * 32 + (lane >> 4) * 8 + j * 2;
        const float* W = (l == 0) ? W0 : ((l == 1) ? W1 : W2);
        Wfrag[i] = packbf(W[k0 * HDIM + n], W[(k0 + 1) * HDIM + n]);
    }
}

// ---------------- phase A: bucket scatter, single global read (register stash) ----------------
__global__ __launch_bounds__(256) void k_bucket(const int* __restrict__ src,
                                                const int* __restrict__ dst,
                                                int* __restrict__ gcur,
                                                unsigned* __restrict__ ebuck) {
    __shared__ int hist[NBUCK];
    __shared__ int base[NBUCK];
    __shared__ int cur[NBUCK];
    const int t = threadIdx.x;
    const int e0 = blockIdx.x * EPB;
    for (int b = t; b < NBUCK; b += 256) hist[b] = 0;
    __syncthreads();
    int bb_[16];
    unsigned vv_[16];
#pragma unroll
    for (int q = 0; q < 16; ++q) {
        int e = e0 + q * 256 + t;
        if (e < N_EDGES) {
            int d = dst[e], s = src[e];
            bb_[q] = d >> 8;
            vv_[q] = ((unsigned)s << 8) | (unsigned)(d & 255);
            atomicAdd(&hist[d >> 8], 1);
        } else {
            bb_[q] = -1;
            vv_[q] = 0;
        }
    }
    __syncthreads();
    for (int b = t; b < NBUCK; b += 256) {
        base[b] = atomicAdd(&gcur[b], hist[b]);
        cur[b] = 0;
    }
    __syncthreads();
#pragma unroll
    for (int q = 0; q < 16; ++q) {
        int b = bb_[q];
        if (b >= 0) {
            int p = base[b] + atomicAdd(&cur[b], 1);
            if (p < SLAB)
                ebuck[(size_t)b * SLAB + p] = vv_[q];
        }
    }
}

// ---------------- phase B: per-bucket sort, 16-padded ranges, rbase/rend/dinv ----------------
// esrc holds src-row BYTE offsets; pad slots keep ZOFF from k_init.
__global__ __launch_bounds__(256) void k_bsort(const int* __restrict__ gcur,
                                               const unsigned* __restrict__ ebuck,
                                               unsigned* __restrict__ esrc,
                                               int* __restrict__ rbase,
                                               int* __restrict__ rend,
                                               float* __restrict__ dinv) {
    __shared__ unsigned stage[SLAB];   // 27.6 KB
    __shared__ int hist[256], offs[256], cur[256];
    __shared__ int wsum[4];
    const int t = threadIdx.x;
    const int b = blockIdx.x;
    const int cnt = min(gcur[b], SLAB);
    hist[t] = 0;
    cur[t] = 0;
    __syncthreads();
    for (int i = t; i < cnt; i += 256) {
        unsigned u = ebuck[(size_t)b * SLAB + i];
        stage[i] = u;
        atomicAdd(&hist[u & 255], 1);
    }
    __syncthreads();
    int v = hist[t];
    int p = (v + 15) & ~15;            // padded to multiple of 16
    int lane = t & 63, wv = t >> 6;
    int incl = p;
#pragma unroll
    for (int o = 1; o < 64; o <<= 1) {
        int tmp = __shfl_up(incl, o);
        if (lane >= o) incl += tmp;
    }
    if (lane == 63) wsum[wv] = incl;
    __syncthreads();
    int woff = 0;
    for (int w = 0; w < wv; ++w) woff += wsum[w];
    int ex = incl - p + woff;          // exclusive scan of padded counts
    offs[t] = ex;
    int d = b * 256 + t;
    if (d < N_NODES) {
        rbase[d] = b * SLAB + min(ex, SLAB);
        rend[d] = b * SLAB + min(ex + p, SLAB);
        dinv[d] = rsqrtf((float)v + 1.0f);
    }
    __syncthreads();
    for (int i = t; i < cnt; i += 256) {
        unsigned u = stage[i];
        int dl = u & 255;
        int pp = atomicAdd(&cur[dl], 1);
        int slot = offs[dl] + pp;
        if (slot < SLAB)
            esrc[(size_t)b * SLAB + slot] = u & 0xFFFFFF00u;
    }
}

// ---------------- MFMA GEMM: Cb = (X @ W) * dinv[row], bf16 out ----------------
// LDS-staged epilogue for coalesced uint4 stores.
__global__ __launch_bounds__(256, 2) void k_mgemm(const uint4* __restrict__ Xb4,
                                                  const float4* __restrict__ Xf4,
                                                  const uint4* __restrict__ Wfrag,
                                                  const float* __restrict__ dinv,
                                                  unsigned short* __restrict__ Cbh) {
    __shared__ __align__(16) unsigned short Cs[64][136];  // row stride 272B
    const int t = threadIdx.x;
    const int lane = t & 63;
    const int w = t >> 6;
    const int brow0 = blockIdx.x * 64;
    const int row0 = brow0 + w * 16;
    const int lhi = lane >> 4;

    FragU B[8][4];
#pragma unroll
    for (int ct = 0; ct < 8; ++ct)
#pragma unroll
        for (int ks = 0; ks < 4; ++ks)
            B[ct][ks].u = Wfrag[(ct * 4 + ks) * 64 + lane];

    f32x4 acc[8];
#pragma unroll
    for (int ct = 0; ct < 8; ++ct) acc[ct] = (f32x4){0.f, 0.f, 0.f, 0.f};

    int arow = row0 + (lane & 15);
    int anode = (arow < N_NODES) ? arow : 0;
#pragma unroll
    for (int ks = 0; ks < 4; ++ks) {
        FragU a;
        if (Xf4) {
            float4 p = Xf4[(size_t)anode * 32 + ks * 8 + lhi * 2];
            float4 q = Xf4[(size_t)anode * 32 + ks * 8 + lhi * 2 + 1];
            a.u.x = packbf(p.x, p.y);
            a.u.y = packbf(p.z, p.w);
            a.u.z = packbf(q.x, q.y);
            a.u.w = packbf(q.z, q.w);
        } else {
            a.u = Xb4[(size_t)anode * 16 + ks * 4 + lhi];
        }
#pragma unroll
        for (int ct = 0; ct < 8; ++ct)
            acc[ct] = __builtin_amdgcn_mfma_f32_16x16x32_bf16(a.s, B[ct][ks].s, acc[ct], 0, 0, 0);
    }

#pragma unroll
    for (int r = 0; r < 4; ++r) {
        int lrow = w * 16 + lhi * 4 + r;
        int grow = brow0 + lrow;
        float dv = dinv[(grow < N_NODES) ? grow : 0];
#pragma unroll
        for (int ct = 0; ct < 8; ++ct)
            Cs[lrow][ct * 16 + (lane & 15)] = (unsigned short)bf16r(acc[ct][r] * dv);
    }
    __syncthreads();
#pragma unroll
    for (int u = 0; u < 4; ++u) {
        int idx = t + u * 256;           // 0..1023
        int row = idx >> 4, q = idx & 15;
        if (brow0 + row < N_NODES) {
            uint4 val = *reinterpret_cast<const uint4*>(&Cs[row][q * 8]);
            *reinterpret_cast<uint4*>(Cbh + ((size_t)(brow0 + row) * HDIM + q * 8)) = val;
        }
    }
}

// ---------------- gather + self + bias + layernorm + relu (bf16 rows) ----------------
// 1 node per wave; padded ranges -> branch-free inner loop (pad slots hit zero row).
__global__ __launch_bounds__(256) void k_gather(const unsigned* __restrict__ Cb,
                                                const int* __restrict__ rbase,
                                                const int* __restrict__ rend,
                                                const unsigned* __restrict__ esrc,
                                                const float* __restrict__ dinv,
                                                const float* __restrict__ b,
                                                const float* __restrict__ g,
                                                const float* __restrict__ be,
                                                unsigned* __restrict__ Ab) {
    const int lane = threadIdx.x & 63;
    const char* cbB = (const char*)Cb;
    const unsigned lb = (unsigned)(lane * 4);
    int wid = (blockIdx.x * blockDim.x + threadIdx.x) >> 6;
    const int nw = (gridDim.x * blockDim.x) >> 6;
    float2 bb = reinterpret_cast<const float2*>(b)[lane];
    float2 gg = reinterpret_cast<const float2*>(g)[lane];
    float2 bee = reinterpret_cast<const float2*>(be)[lane];
    for (int i = wid; i < N_NODES; i += nw) {
        int r0 = rbase[i], r1 = rend[i];
        float ax = 0.f, ay = 0.f;
        for (int j = r0; j < r1; j += 16) {
            unsigned off[16];
#pragma unroll
            for (int q = 0; q < 16; ++q) off[q] = esrc[j + q];
            unsigned u[16];
#pragma unroll
            for (int q = 0; q < 16; ++q)
                u[q] = *reinterpret_cast<const unsigned*>(cbB + (off[q] + lb));
#pragma unroll
            for (int q = 0; q < 16; ++q) {
                ax += __uint_as_float(u[q] << 16);
                ay += __uint_as_float(u[q]);       // junk low mantissa, <0.8% rel
            }
        }
        // self-loop (row already dinv-scaled)
        unsigned us = *reinterpret_cast<const unsigned*>(cbB + (((unsigned)i << 8) + lb));
        ax += __uint_as_float(us << 16);
        ay += __uint_as_float(us);
        float di = dinv[i];
        float vx = ax * di + bb.x;
        float vy = ay * di + bb.y;
        float s = vx + vy, sq = vx * vx + vy * vy;
#pragma unroll
        for (int o = 1; o < 64; o <<= 1) {
            s += __shfl_xor(s, o);
            sq += __shfl_xor(sq, o);
        }
        float m = s * (1.0f / HDIM);
        float var = sq * (1.0f / HDIM) - m * m;
        float rs = rsqrtf(var + 1e-5f);
        float ox = fmaxf((vx - m) * rs * gg.x + bee.x, 0.f);
        float oy = fmaxf((vy - m) * rs * gg.y + bee.y, 0.f);
        Ab[(size_t)i * HP + lane] = packbf(ox, oy);
    }
}

// ---------------- pool: pooled[batch[i]] += A[i] (bf16 rows, sorted batch) ----------------
__global__ __launch_bounds__(256) void k_pool(const unsigned* __restrict__ Ab,
                                              const int* __restrict__ batch,
                                              float* __restrict__ pooled) {
    const int CH = 16;
    const int lane = threadIdx.x & 63;
    int wid = (blockIdx.x * blockDim.x + threadIdx.x) >> 6;
    const int nw = (gridDim.x * blockDim.x) >> 6;
    const int nchunks = (N_NODES + CH - 1) / CH;
    for (int c = wid; c < nchunks; c += nw) {
        int i0 = c * CH;
        int i1 = min(i0 + CH, N_NODES);
        float ax = 0.f, ay = 0.f;
        int curb = batch[i0];
        for (int i = i0; i < i1; ++i) {
            int bg = batch[i];
            if (bg != curb) {
                float* p = pooled + (size_t)curb * HDIM + lane * 2;
                atomicAdd(p, ax);
                atomicAdd(p + 1, ay);
                ax = 0.f; ay = 0.f;
                curb = bg;
            }
            unsigned v = Ab[(size_t)i * HP + lane];
            ax += bflo(v);
            ay += bfhi(v);
        }
        float* p = pooled + (size_t)curb * HDIM + lane * 2;
        atomicAdd(p, ax);
        atomicAdd(p + 1, ay);
    }
}

// ---------------- head: out = pooled @ Wf + bf ----------------
__global__ __launch_bounds__(256) void k_head(const float* __restrict__ pooled,
                                              const float* __restrict__ Wf,
                                              const float* __restrict__ bf,
                                              float* __restrict__ out) {
    int idx = blockIdx.x * blockDim.x + threadIdx.x;
    if (idx >= N_GRAPHS * OUTDIM) return;
    int gI = idx / OUTDIM;
    int o = idx % OUTDIM;
    float acc = bf[o];
    const float* pr = pooled + (size_t)gI * HDIM;
#pragma unroll 8
    for (int k = 0; k < HDIM; ++k) acc += pr[k] * Wf[k * OUTDIM + o];
    out[idx] = acc;
}

extern "C" void kernel_launch(void* const* d_in, const int* in_sizes, int n_in,
                              void* d_out, int out_size, void* d_ws, size_t ws_size,
                              hipStream_t stream) {
    const float* x = (const float*)d_in[0];
    const int* ei = (const int*)d_in[1];
    const int* src = ei;
    const int* dst = ei + N_EDGES;
    const int* batch = (const int*)d_in[2];
    const float* W[3] = {(const float*)d_in[3], (const float*)d_in[7], (const float*)d_in[11]};
    const float* bb[3] = {(const float*)d_in[4], (const float*)d_in[8], (const float*)d_in[12]};
    const float* gg[3] = {(const float*)d_in[5], (const float*)d_in[9], (const float*)d_in[13]};
    const float* be[3] = {(const float*)d_in[6], (const float*)d_in[10], (const float*)d_in[14]};
    const float* Wf = (const float*)d_in[15];
    const float* bf = (const float*)d_in[16];
    float* out = (float*)d_out;

    char* ws = (char*)d_ws;
    float* dinv = (float*)ws;        ws += sizeof(float) * (N_NODES + 64);
    unsigned* Ab = (unsigned*)ws;    ws += sizeof(unsigned) * (size_t)N_NODES * HP;
    unsigned* Cb = (unsigned*)ws;    ws += sizeof(unsigned) * ((size_t)N_NODES * HP + HP);  // +1 zero row
    unsigned* Wfrag = (unsigned*)ws; ws += sizeof(unsigned) * 3 * 8192;
    float* pooled = (float*)ws;      ws += sizeof(float) * N_GRAPHS * HDIM;
    int* rbase = (int*)ws;           ws += sizeof(int) * (N_NODES + 64);
    int* rend = (int*)ws;            ws += sizeof(int) * (N_NODES + 64);
    int* gcur = (int*)ws;            ws += sizeof(int) * (NBUCK + 64);
    unsigned* ebuck = (unsigned*)ws; ws += sizeof(unsigned) * (size_t)NBUCK * SLAB;
    unsigned* esrc = (unsigned*)ws;  ws += sizeof(unsigned) * ((size_t)NBUCK * SLAB + 64);

    unsigned* zrow = Cb + (size_t)N_NODES * HP;
    k_init<<<2048, 256, 0, stream>>>(W[0], W[1], W[2], Wfrag, esrc, pooled, gcur, zrow);
    k_bucket<<<(N_EDGES + EPB - 1) / EPB, 256, 0, stream>>>(src, dst, gcur, ebuck);
    k_bsort<<<NBUCK, 256, 0, stream>>>(gcur, ebuck, esrc, rbase, rend, dinv);

    const int gemm_blocks = (N_NODES + 63) / 64;
    for (int l = 0; l < 3; ++l) {
        k_mgemm<<<gemm_blocks, 256, 0, stream>>>(
            l == 0 ? nullptr : (const uint4*)Ab,
            l == 0 ? (const float4*)x : nullptr,
            (const uint4*)(Wfrag + l * 8192), dinv, (unsigned short*)Cb);
        k_gather<<<25000, 256, 0, stream>>>(Cb, rbase, rend, esrc, dinv,
                                            bb[l], gg[l], be[l], Ab);
    }

    k_pool<<<1563, 256, 0, stream>>>(Ab, batch, pooled);
    k_head<<<(N_GRAPHS * OUTDIM + 255) / 256, 256, 0, stream>>>(pooled, Wf, bf, out);
}